// Round 7
// baseline (876.278 us; speedup 1.0000x reference)
//
#include <hip/hip_runtime.h>
#include <math.h>

// ---------------------------------------------------------------------------
// Round 15: 2-stream ILP. R14: VALUBusy 59%, MfmaUtil 17%, 4 waves/SIMD,
//   long serial dep chain per wave -> latency-bound (2 rounds of VALU
//   stripping converted at ~0.55x). R13 proved LDS can't shrink (weights
//   must stay) so TLP is walled; this round converts TLP->ILP:
//   8 waves x 512 threads, each wave runs TWO independent 16-sample streams
//   (rows wave*16 and wave*16+128). Same 16 TH buffers (2/wave), same arena,
//   same verified layouts/math. Every A-frag ds_read now feeds 2 MFMAs
//   (layerN2 / layerB4 / ffn2_via_th2) -> per-sample A-read traffic halves,
//   and two independent dep chains fill the issue bubbles.
//   __launch_bounds__(512,1): 1 block/CU, 2 waves/SIMD, 256-VGPR cap.
// ---------------------------------------------------------------------------

constexpr int STEPS = 16;
constexpr int INDIM = 200;

typedef __attribute__((ext_vector_type(8))) short bfrag8;   // 8 bf16 = 4 VGPR
typedef __attribute__((ext_vector_type(4))) float f32x4;
typedef __attribute__((ext_vector_type(4))) short s16x4;

constexpr int FB_WIN  = 0;    // W_in: mt(4) x kt(7)
constexpr int NFRAG   = 140;
constexpr int NPARAM  = 1544;

// LDS-resident steady frag indices (= global index - 28)
constexpr int LB_ZQ   = 0;
constexpr int LB_ZK   = 8;
constexpr int LB_ZV   = 16;
constexpr int LB_ZOUT = 24;
constexpr int LB_ZF1  = 32;
constexpr int LB_ZF2  = 48;
constexpr int LB_YV   = 64;
constexpr int LB_YOUT = 72;
constexpr int LB_YF1  = 80;
constexpr int LB_YF2  = 96;
constexpr int NSTEADY = 112;

// packed param float offsets
constexpr int PB_BIN   = 0;
constexpr int PB_GIN   = 64;
constexpr int PB_BEIN  = 128;
constexpr int PB_ZINB  = 192;
constexpr int PB_ZOUTB = 384;
constexpr int PB_ZF1B  = 448;
constexpr int PB_ZF2B  = 576;
constexpr int PB_ZN1G  = 640;
constexpr int PB_ZN1B  = 704;
constexpr int PB_ZN2G  = 768;
constexpr int PB_ZN2B  = 832;
constexpr int PB_YVB   = 896;
constexpr int PB_YOUTB = 960;
constexpr int PB_YF1B  = 1024;
constexpr int PB_YF2B  = 1152;
constexpr int PB_YN1G  = 1216;
constexpr int PB_YN1B  = 1280;
constexpr int PB_YN2G  = 1344;
constexpr int PB_YN2B  = 1408;
constexpr int PB_WOUT  = 1472;
constexpr int PB_BOUT  = 1536;

// LDS arena layout (shorts)
constexpr int S64      = 72;
constexpr int L_W      = 0;                       // 112 frags = 57,344 shorts
constexpr int L_P      = 57344;                   // 3,088 shorts
constexpr int L_ACT    = 60432;                   // 8 waves x 2 streams x TH
constexpr int WAVE_SH  = 1152;                    // 16 samples x 72 shorts
constexpr int NWAVE    = 16;                      // buffers (8 waves x 2)
constexpr int ARENA_SH = L_ACT + NWAVE * WAVE_SH; // 78,864 shorts = 157,728 B

struct Params {
  const float *x, *W_in, *b_in, *g_in, *be_in;
  const float *z_in_w, *z_in_b, *z_out_w, *z_out_b;
  const float *z_ffn_w1, *z_ffn_b1, *z_ffn_w2, *z_ffn_b2;
  const float *zn1_g, *zn1_b, *zn2_g, *zn2_b;
  const float *y_in_w, *y_in_b, *y_out_w, *y_out_b;
  const float *y_ffn_w1, *y_ffn_b1, *y_ffn_w2, *y_ffn_b2;
  const float *yn1_g, *yn1_b, *yn2_g, *yn2_b;
  const float *W_out, *b_out;
  float *out;
  int nrows;
};

// Cold-path (prepack) conversion: exact round-to-nearest-even.
__device__ __forceinline__ ushort f2bf_rne(float f) {
  uint u = __float_as_uint(f);
  u += 0x7FFFu + ((u >> 16) & 1u);
  return (ushort)(u >> 16);
}

// Hot-path conversion: round-half-up (1 add).
__device__ __forceinline__ ushort f2bf(float f) {
  return (ushort)((__float_as_uint(f) + 0x8000u) >> 16);
}
__device__ __forceinline__ uint pk2(float a, float b) {
  uint ua = __float_as_uint(a) + 0x8000u;
  uint ub = __float_as_uint(b) + 0x8000u;
  return (ua >> 16) | (ub & 0xFFFF0000u);
}
__device__ __forceinline__ float upk_lo(uint u) {
  return __uint_as_float(u << 16);
}
__device__ __forceinline__ float upk_hi(uint u) {
  return __uint_as_float(u & 0xFFFF0000u);
}
__device__ __forceinline__ f32x4 upk4(const uint* p) {
  f32x4 r;
  r.x = upk_lo(p[0]); r.y = upk_hi(p[0]);
  r.z = upk_lo(p[1]); r.w = upk_hi(p[1]);
  return r;
}
__device__ __forceinline__ float dot4(f32x4 a, f32x4 b) {
  return a.x * b.x + a.y * b.y + a.z * b.z + a.w * b.w;
}
__device__ __forceinline__ void stc(short* buf, int stride, int mt, int q,
                                    int s, f32x4 c) {
  s16x4 v;
  v.x = (short)f2bf(c.x); v.y = (short)f2bf(c.y);
  v.z = (short)f2bf(c.z); v.w = (short)f2bf(c.w);
  *(s16x4*)(buf + s * stride + mt * 16 + q * 4) = v;
}

// C-layout (packed bf16 pairs p[8]) -> 2 MFMA B-frags. Verified in R4.
__device__ __forceinline__ void c2b_p(const uint p[8], bfrag8& b0, bfrag8& b1,
                                      int lane) {
  const int srcA = (lane & 15) | ((lane & 16) << 1);  // s + 32*(q&1)
  const int srcB = srcA + 16;
  const bool odd = (lane & 32) != 0;                  // q>=2 wants mt 1,3
  uint ev0 = p[0], ev1 = p[1], ev2 = p[4], ev3 = p[5];
  uint od0 = p[2], od1 = p[3], od2 = p[6], od3 = p[7];
  uint rA0, rA1, rA2, rA3, rB0, rB1, rB2, rB3;
  {
    uint e, o;
    e = (uint)__shfl((int)ev0, srcA); o = (uint)__shfl((int)od0, srcA); rA0 = odd ? o : e;
    e = (uint)__shfl((int)ev1, srcA); o = (uint)__shfl((int)od1, srcA); rA1 = odd ? o : e;
    e = (uint)__shfl((int)ev2, srcA); o = (uint)__shfl((int)od2, srcA); rA2 = odd ? o : e;
    e = (uint)__shfl((int)ev3, srcA); o = (uint)__shfl((int)od3, srcA); rA3 = odd ? o : e;
    e = (uint)__shfl((int)ev0, srcB); o = (uint)__shfl((int)od0, srcB); rB0 = odd ? o : e;
    e = (uint)__shfl((int)ev1, srcB); o = (uint)__shfl((int)od1, srcB); rB1 = odd ? o : e;
    e = (uint)__shfl((int)ev2, srcB); o = (uint)__shfl((int)od2, srcB); rB2 = odd ? o : e;
    e = (uint)__shfl((int)ev3, srcB); o = (uint)__shfl((int)od3, srcB); rB3 = odd ? o : e;
  }
  union U { uint u[4]; bfrag8 b; };
  U u0, u1;
  u0.u[0] = rA0; u0.u[1] = rA1; u0.u[2] = rB0; u0.u[3] = rB1;
  u1.u[0] = rA2; u1.u[1] = rA3; u1.u[2] = rB2; u1.u[3] = rB3;
  b0 = u0.b; b1 = u1.b;
}
__device__ __forceinline__ void c2b(const f32x4 c[4], bfrag8& b0, bfrag8& b1,
                                    int lane) {
  uint p[8];
#pragma unroll
  for (int mt = 0; mt < 4; ++mt) {
    p[2 * mt]     = pk2(c[mt].x, c[mt].y);
    p[2 * mt + 1] = pk2(c[mt].z, c[mt].w);
  }
  c2b_p(p, b0, b1, lane);
}

// Two TH streams through the same weights: A-frag read once.
template <int MT>
__device__ __forceinline__ void layerN2(const short* in0, const short* in1,
                                        const short* lw, int fbase,
                                        const float* bias, f32x4* c0, f32x4* c1,
                                        int lane, int q, int s) {
  bfrag8 b0[2], b1[2];
#pragma unroll
  for (int kt = 0; kt < 2; ++kt) {
    b0[kt] = *(const bfrag8*)(in0 + s * S64 + kt * 32 + q * 8);
    b1[kt] = *(const bfrag8*)(in1 + s * S64 + kt * 32 + q * 8);
  }
#pragma unroll
  for (int mt = 0; mt < MT; ++mt) {
    f32x4 b4 = *(const f32x4*)(bias + mt * 16 + q * 4);
    c0[mt] = b4; c1[mt] = b4;
  }
#pragma unroll
  for (int mt = 0; mt < MT; ++mt) {
#pragma unroll
    for (int kt = 0; kt < 2; ++kt) {
      bfrag8 af = *(const bfrag8*)(lw + (fbase + mt * 2 + kt) * 512 + lane * 8);
      c0[mt] = __builtin_amdgcn_mfma_f32_16x16x32_bf16(af, b0[kt], c0[mt], 0, 0, 0);
      c1[mt] = __builtin_amdgcn_mfma_f32_16x16x32_bf16(af, b1[kt], c1[mt], 0, 0, 0);
    }
  }
}

// Two register-B inputs through the same weights.
template <int MT>
__device__ __forceinline__ void layerB2(const bfrag8* bfA, const bfrag8* bfB,
                                        const short* lw, int fbase,
                                        const float* bias, f32x4* cA, f32x4* cB,
                                        int lane, int q) {
#pragma unroll
  for (int mt = 0; mt < MT; ++mt) {
    f32x4 b4 = *(const f32x4*)(bias + mt * 16 + q * 4);
    cA[mt] = b4; cB[mt] = b4;
  }
#pragma unroll
  for (int mt = 0; mt < MT; ++mt) {
#pragma unroll
    for (int kt = 0; kt < 2; ++kt) {
      bfrag8 af = *(const bfrag8*)(lw + (fbase + mt * 2 + kt) * 512 + lane * 8);
      cA[mt] = __builtin_amdgcn_mfma_f32_16x16x32_bf16(af, bfA[kt], cA[mt], 0, 0, 0);
      cB[mt] = __builtin_amdgcn_mfma_f32_16x16x32_bf16(af, bfB[kt], cB[mt], 0, 0, 0);
    }
  }
}

// Four register-B inputs through the same weights: A-frag read once.
template <int MT>
__device__ __forceinline__ void layerB4(const bfrag8* bf0, const bfrag8* bf1,
                                        const bfrag8* bf2, const bfrag8* bf3,
                                        const short* lw, int fbase,
                                        const float* bias, f32x4* c0, f32x4* c1,
                                        f32x4* c2, f32x4* c3, int lane, int q) {
#pragma unroll
  for (int mt = 0; mt < MT; ++mt) {
    f32x4 b4 = *(const f32x4*)(bias + mt * 16 + q * 4);
    c0[mt] = b4; c1[mt] = b4; c2[mt] = b4; c3[mt] = b4;
  }
#pragma unroll
  for (int mt = 0; mt < MT; ++mt) {
#pragma unroll
    for (int kt = 0; kt < 2; ++kt) {
      bfrag8 af = *(const bfrag8*)(lw + (fbase + mt * 2 + kt) * 512 + lane * 8);
      c0[mt] = __builtin_amdgcn_mfma_f32_16x16x32_bf16(af, bf0[kt], c0[mt], 0, 0, 0);
      c1[mt] = __builtin_amdgcn_mfma_f32_16x16x32_bf16(af, bf1[kt], c1[mt], 0, 0, 0);
      c2[mt] = __builtin_amdgcn_mfma_f32_16x16x32_bf16(af, bf2[kt], c2[mt], 0, 0, 0);
      c3[mt] = __builtin_amdgcn_mfma_f32_16x16x32_bf16(af, bf3[kt], c3[mt], 0, 0, 0);
    }
  }
}

// Vectorized layernorm.
__device__ __forceinline__ void lnorm_c(f32x4 c[4], const float* g,
                                        const float* b, int q) {
  f32x4 s4 = (c[0] + c[1]) + (c[2] + c[3]);
  float sm = (s4.x + s4.y) + (s4.z + s4.w);
  sm += __shfl_xor(sm, 16); sm += __shfl_xor(sm, 32);
  float mean = sm * (1.f / 64.f);
  f32x4 vs4 = {0.f, 0.f, 0.f, 0.f};
#pragma unroll
  for (int mt = 0; mt < 4; ++mt) {
    f32x4 d = c[mt] - mean;
    c[mt] = d;
    vs4 = vs4 + d * d;
  }
  float vs = (vs4.x + vs4.y) + (vs4.z + vs4.w);
  vs += __shfl_xor(vs, 16); vs += __shfl_xor(vs, 32);
  float rs = rsqrtf(vs * (1.f / 64.f) + 1e-5f);
#pragma unroll
  for (int mt = 0; mt < 4; ++mt) {
    f32x4 g4 = *(const f32x4*)(g + mt * 16 + q * 4);
    f32x4 b4 = *(const f32x4*)(b + mt * 16 + q * 4);
    c[mt] = (c[mt] * rs) * g4 + b4;
  }
}

// Vectorized gelu (3-term A&S 7.1.25 erf).
__device__ __forceinline__ f32x4 gelu4(f32x4 x) {
  const float K = 0.70710678118654752f;
  f32x4 ax;
  ax.x = fabsf(x.x) * K; ax.y = fabsf(x.y) * K;
  ax.z = fabsf(x.z) * K; ax.w = fabsf(x.w) * K;
  f32x4 u = ax * 0.47047f + 1.0f;
  f32x4 t;
  t.x = __builtin_amdgcn_rcpf(u.x); t.y = __builtin_amdgcn_rcpf(u.y);
  t.z = __builtin_amdgcn_rcpf(u.z); t.w = __builtin_amdgcn_rcpf(u.w);
  f32x4 poly = ((t * 0.7478556f + (-0.0958798f)) * t + 0.3480242f) * t;
  f32x4 gq = ax * ax;
  f32x4 e;
  e.x = __expf(-gq.x); e.y = __expf(-gq.y);
  e.z = __expf(-gq.z); e.w = __expf(-gq.w);
  f32x4 r = poly * e;
  f32x4 er;
  er.x = copysignf(1.0f - r.x, x.x); er.y = copysignf(1.0f - r.y, x.y);
  er.z = copysignf(1.0f - r.z, x.z); er.w = copysignf(1.0f - r.w, x.w);
  f32x4 h = x * 0.5f;
  return h + h * er;
}

// FFN tail for 2 streams: gelu(h) -> TH halves -> B-frags -> FFN2 MFMAs,
// A-frags read once per (mt,kt) for both streams.
__device__ __forceinline__ void ffn2_via_th2(const f32x4 h0[8], const f32x4 h1[8],
                                             short* TH0, short* TH1,
                                             const short* lw, int f2base,
                                             const float* b2, f32x4 c0[4],
                                             f32x4 c1[4], int lane, int q, int s) {
#pragma unroll
  for (int mt = 0; mt < 4; ++mt) {
    f32x4 b4 = *(const f32x4*)(b2 + mt * 16 + q * 4);
    c0[mt] = b4; c1[mt] = b4;
  }
#pragma unroll
  for (int g = 0; g < 2; ++g) {
#pragma unroll
    for (int mt = 0; mt < 4; ++mt) {
      stc(TH0, S64, mt, q, s, gelu4(h0[4 * g + mt]));
      stc(TH1, S64, mt, q, s, gelu4(h1[4 * g + mt]));
    }
    bfrag8 bf0[2], bf1[2];
#pragma unroll
    for (int kt = 0; kt < 2; ++kt) {
      bf0[kt] = *(const bfrag8*)(TH0 + s * S64 + kt * 32 + q * 8);
      bf1[kt] = *(const bfrag8*)(TH1 + s * S64 + kt * 32 + q * 8);
    }
#pragma unroll
    for (int mt = 0; mt < 4; ++mt) {
#pragma unroll
      for (int kt = 0; kt < 2; ++kt) {
        bfrag8 af =
            *(const bfrag8*)(lw + (f2base + mt * 4 + 2 * g + kt) * 512 + lane * 8);
        c0[mt] = __builtin_amdgcn_mfma_f32_16x16x32_bf16(af, bf0[kt], c0[mt], 0, 0, 0);
        c1[mt] = __builtin_amdgcn_mfma_f32_16x16x32_bf16(af, bf1[kt], c1[mt], 0, 0, 0);
      }
    }
  }
}

// ---------------------------------------------------------------------------
// prepack: weights -> A-frag bf16 order; params -> packed fp32 array
// ---------------------------------------------------------------------------
__global__ void prepack_kernel(Params p, ushort* wf) {
  int f = blockIdx.x;
  int lane = threadIdx.x;

  if (f == NFRAG) {
    float* pw = (float*)(wf + (size_t)NFRAG * 512);
    for (int t = lane; t < NPARAM; t += 64) {
      float v = 0.f;
      if      (t < 64)   v = p.b_in[t];
      else if (t < 128)  v = p.g_in[t - 64];
      else if (t < 192)  v = p.be_in[t - 128];
      else if (t < 384)  v = p.z_in_b[t - 192];
      else if (t < 448)  v = p.z_out_b[t - 384];
      else if (t < 576)  v = p.z_ffn_b1[t - 448];
      else if (t < 640)  v = p.z_ffn_b2[t - 576];
      else if (t < 704)  v = p.zn1_g[t - 640];
      else if (t < 768)  v = p.zn1_b[t - 704];
      else if (t < 832)  v = p.zn2_g[t - 768];
      else if (t < 896)  v = p.zn2_b[t - 832];
      else if (t < 960)  v = p.y_in_b[128 + t - 896];
      else if (t < 1024) v = p.y_out_b[t - 960];
      else if (t < 1152) v = p.y_ffn_b1[t - 1024];
      else if (t < 1216) v = p.y_ffn_b2[t - 1152];
      else if (t < 1280) v = p.yn1_g[t - 1216];
      else if (t < 1344) v = p.yn1_b[t - 1280];
      else if (t < 1408) v = p.yn2_g[t - 1344];
      else if (t < 1472) v = p.yn2_b[t - 1408];
      else if (t < 1536) v = p.W_out[t - 1472];
      else if (t == 1536) v = p.b_out[0];
      pw[t] = v;
    }
    return;
  }

  int q = lane >> 4, r = lane & 15;
  const float* src; int K, mt, kt, l;
  if (f < 28)        { src = p.W_in;                K = 200; mt = f / 7;  kt = f % 7; }
  else if (f < 36)   { l = f - 28;  src = p.z_in_w;            K = 64;  mt = l / 2; kt = l % 2; }
  else if (f < 44)   { l = f - 36;  src = p.z_in_w + 64 * 64;  K = 64;  mt = l / 2; kt = l % 2; }
  else if (f < 52)   { l = f - 44;  src = p.z_in_w + 128 * 64; K = 64;  mt = l / 2; kt = l % 2; }
  else if (f < 60)   { l = f - 52;  src = p.z_out_w;           K = 64;  mt = l / 2; kt = l % 2; }
  else if (f < 76)   { l = f - 60;  src = p.z_ffn_w1;          K = 64;  mt = l / 2; kt = l % 2; }
  else if (f < 92)   { l = f - 76;  src = p.z_ffn_w2;          K = 128; mt = l / 4; kt = l % 4; }
  else if (f < 100)  { l = f - 92;  src = p.y_in_w + 128 * 64; K = 64;  mt = l / 2; kt = l % 2; }
  else if (f < 108)  { l = f - 100; src = p.y_out_w;           K = 64;  mt = l / 2; kt = l % 2; }
  else if (f < 124)  { l = f - 108; src = p.y_ffn_w1;          K = 64;  mt = l / 2; kt = l % 2; }
  else               { l = f - 124; src = p.y_ffn_w2;          K = 128; mt = l / 4; kt = l % 4; }

  int row = mt * 16 + r;
  int col = kt * 32 + q * 8;
  bfrag8 o;
#pragma unroll
  for (int j = 0; j < 8; ++j) {
    int cc = col + j;
    float v = (cc < K) ? src[(size_t)row * K + cc] : 0.0f;
    o[j] = (short)f2bf_rne(v);
  }
  *(bfrag8*)(wf + (size_t)f * 512 + lane * 8) = o;
}

// ---------------------------------------------------------------------------
// main kernel: 512 thr (8 waves) x 256 blocks; 1 block/CU, 2 waves/SIMD
// (256-VGPR cap), 2 independent streams per wave.
// ---------------------------------------------------------------------------
__global__ __launch_bounds__(512, 1)
void trm_mfma_kernel(Params p, const ushort* wf) {
  __shared__ __align__(16) short arena[ARENA_SH];
  const int tid = threadIdx.x;
  const int wave = tid >> 6, lane = tid & 63;
  const int q = lane >> 4, s = lane & 15;

  // ---- stage steady weights + params into LDS (once per block) ----
  {
    const uint4* srcw = (const uint4*)(wf + (size_t)28 * 512);
    uint4* dstw = (uint4*)(arena + L_W);
    for (int i = tid; i < NSTEADY * 64; i += 512) dstw[i] = srcw[i];
    const uint4* srcp = (const uint4*)(wf + (size_t)NFRAG * 512);
    uint4* dstp = (uint4*)(arena + L_P);
    for (int i = tid; i < NPARAM / 4; i += 512) dstp[i] = srcp[i];
  }
  __syncthreads();  // the only barrier

  const short* LW = arena + L_W;
  const float* P  = (const float*)(arena + L_P);
  short* TH0 = arena + L_ACT + (2 * wave) * WAVE_SH;
  short* TH1 = TH0 + WAVE_SH;

  const int chunks = (p.nrows + 255) / 256;
  for (int ic = blockIdx.x; ic < chunks; ic += gridDim.x) {
    // stream t handles rows [ic*256 + wave*16 + t*128 + s]
    int rw[2];
#pragma unroll
    for (int t = 0; t < 2; ++t) {
      int r = ic * 256 + wave * 16 + t * 128 + s;
      rw[t] = (r < p.nrows) ? r : (p.nrows - 1);
    }

    // ---- x_proj for both streams; W_in A-frags shared ----
    bfrag8 xpB[2][2];
    {
      bfrag8 xb[2][7];
#pragma unroll
      for (int t = 0; t < 2; ++t) {
        const float* xr = p.x + (size_t)rw[t] * INDIM;
#pragma unroll
        for (int kt = 0; kt < 7; ++kt) {
          int k0i = kt * 32 + q * 8;
          bfrag8 v;
          if (kt < 6 || q == 0) {
            f32x4 lo = *(const f32x4*)(xr + k0i);
            f32x4 hi = *(const f32x4*)(xr + k0i + 4);
            v[0] = (short)f2bf(lo.x); v[1] = (short)f2bf(lo.y);
            v[2] = (short)f2bf(lo.z); v[3] = (short)f2bf(lo.w);
            v[4] = (short)f2bf(hi.x); v[5] = (short)f2bf(hi.y);
            v[6] = (short)f2bf(hi.z); v[7] = (short)f2bf(hi.w);
          } else {
#pragma unroll
            for (int j = 0; j < 8; ++j) v[j] = 0;
          }
          xb[t][kt] = v;
        }
      }
      f32x4 c[2][4];
#pragma unroll
      for (int mt = 0; mt < 4; ++mt) {
        f32x4 b4 = *(const f32x4*)(P + PB_BIN + mt * 16 + q * 4);
        c[0][mt] = b4; c[1][mt] = b4;
      }
#pragma unroll
      for (int mt = 0; mt < 4; ++mt)
#pragma unroll
        for (int kt = 0; kt < 7; ++kt) {
          bfrag8 af =
              *(const bfrag8*)(wf + (size_t)(FB_WIN + mt * 7 + kt) * 512 + lane * 8);
          c[0][mt] = __builtin_amdgcn_mfma_f32_16x16x32_bf16(af, xb[0][kt], c[0][mt], 0, 0, 0);
          c[1][mt] = __builtin_amdgcn_mfma_f32_16x16x32_bf16(af, xb[1][kt], c[1][mt], 0, 0, 0);
        }
#pragma unroll
      for (int t = 0; t < 2; ++t) {
        lnorm_c(c[t], P + PB_GIN, P + PB_BEIN, q);
#pragma unroll
        for (int mt = 0; mt < 4; ++mt) c[t][mt] = gelu4(c[t][mt]);
        c2b(c[t], xpB[t][0], xpB[t][1], lane);
      }
    }

    // ---- k0/v0 packed; zero state (per stream) ----
    uint k0p[2][8], v0p[2][8], zCp[2][8], yCp[2][8];
    bfrag8 zB[2][2], yB[2][2];
    {
      f32x4 ck[2][4], cv[2][4];
      layerB2<4>(xpB[0], xpB[1], LW, LB_ZK, P + PB_ZINB + 64, ck[0], ck[1], lane, q);
      layerB2<4>(xpB[0], xpB[1], LW, LB_ZV, P + PB_ZINB + 128, cv[0], cv[1], lane, q);
#pragma unroll
      for (int t = 0; t < 2; ++t) {
#pragma unroll
        for (int mt = 0; mt < 4; ++mt) {
          k0p[t][2 * mt]     = pk2(ck[t][mt].x, ck[t][mt].y);
          k0p[t][2 * mt + 1] = pk2(ck[t][mt].z, ck[t][mt].w);
          v0p[t][2 * mt]     = pk2(cv[t][mt].x, cv[t][mt].y);
          v0p[t][2 * mt + 1] = pk2(cv[t][mt].z, cv[t][mt].w);
          zCp[t][2 * mt] = 0u; zCp[t][2 * mt + 1] = 0u;
          yCp[t][2 * mt] = 0u; yCp[t][2 * mt + 1] = 0u;
        }
#pragma unroll
        for (int kt = 0; kt < 2; ++kt) {
          bfrag8 zr0;
#pragma unroll
          for (int j = 0; j < 8; ++j) zr0[j] = 0;
          zB[t][kt] = zr0; yB[t][kt] = zr0;
        }
      }
    }

    // ---- 16 recursive steps ----
    for (int st = 0; st < STEPS; ++st) {
      // -- attention k-phase --
      float w0[2][4], w1[2][4], w2[2][4], wi[2][4];
      {
        f32x4 q2[2][4], kz[2][4], ky[2][4];
        layerB2<4>(zB[0], zB[1], LW, LB_ZQ, P + PB_ZINB, q2[0], q2[1], lane, q);
        layerB4<4>(zB[0], yB[0], zB[1], yB[1], LW, LB_ZK, P + PB_ZINB + 64,
                   kz[0], ky[0], kz[1], ky[1], lane, q);
#pragma unroll
        for (int t = 0; t < 2; ++t) {
#pragma unroll
          for (int mt = 0; mt < 4; ++mt) {
            float a0 = dot4(q2[t][mt], upk4(k0p[t] + 2 * mt));
            float a1 = dot4(q2[t][mt], ky[t][mt]);
            float a2 = dot4(q2[t][mt], kz[t][mt]);
            a0 += __shfl_xor(a0, 16); a0 += __shfl_xor(a0, 32);
            a1 += __shfl_xor(a1, 16); a1 += __shfl_xor(a1, 32);
            a2 += __shfl_xor(a2, 16); a2 += __shfl_xor(a2, 32);
            a0 *= 0.25f; a1 *= 0.25f; a2 *= 0.25f;
            float mx = fmaxf(a0, fmaxf(a1, a2));
            float e0 = __expf(a0 - mx), e1 = __expf(a1 - mx), e2 = __expf(a2 - mx);
            w0[t][mt] = e0; w1[t][mt] = e1; w2[t][mt] = e2;
            wi[t][mt] = __builtin_amdgcn_rcpf(e0 + e1 + e2);
          }
        }
      }
      // -- attention v-phase --
      {
        f32x4 vz[2][4], vy[2][4];
        layerB4<4>(zB[0], yB[0], zB[1], yB[1], LW, LB_ZV, P + PB_ZINB + 128,
                   vz[0], vy[0], vz[1], vy[1], lane, q);
#pragma unroll
        for (int mt = 0; mt < 4; ++mt) {
          f32x4 o0 = (upk4(v0p[0] + 2 * mt) * w0[0][mt] + vy[0][mt] * w1[0][mt] +
                      vz[0][mt] * w2[0][mt]) * wi[0][mt];
          stc(TH0, S64, mt, q, s, o0);
          f32x4 o1 = (upk4(v0p[1] + 2 * mt) * w0[1][mt] + vy[1][mt] * w1[1][mt] +
                      vz[1][mt] * w2[1][mt]) * wi[1][mt];
          stc(TH1, S64, mt, q, s, o1);
        }
      }

      // -- z branch --
      uint zrp[2][8];
      {
        f32x4 zr[2][4];
        layerN2<4>(TH0, TH1, LW, LB_ZOUT, P + PB_ZOUTB, zr[0], zr[1], lane, q, s);
#pragma unroll
        for (int t = 0; t < 2; ++t) {
#pragma unroll
          for (int mt = 0; mt < 4; ++mt) zr[t][mt] = zr[t][mt] + upk4(zCp[t] + 2 * mt);
          lnorm_c(zr[t], P + PB_ZN1G, P + PB_ZN1B, q);
        }
#pragma unroll
        for (int mt = 0; mt < 4; ++mt) {
          stc(TH0, S64, mt, q, s, zr[0][mt]);
          stc(TH1, S64, mt, q, s, zr[1][mt]);
        }
#pragma unroll
        for (int t = 0; t < 2; ++t)
#pragma unroll
          for (int mt = 0; mt < 4; ++mt) {
            zrp[t][2 * mt]     = pk2(zr[t][mt].x, zr[t][mt].y);
            zrp[t][2 * mt + 1] = pk2(zr[t][mt].z, zr[t][mt].w);
          }
      }

      // z-FFN
      f32x4 z2[2][4];
      {
        f32x4 h8[2][8];
        layerN2<8>(TH0, TH1, LW, LB_ZF1, P + PB_ZF1B, h8[0], h8[1], lane, q, s);
        ffn2_via_th2(h8[0], h8[1], TH0, TH1, LW, LB_ZF2, P + PB_ZF2B,
                     z2[0], z2[1], lane, q, s);
      }
#pragma unroll
      for (int t = 0; t < 2; ++t) {
#pragma unroll
        for (int mt = 0; mt < 4; ++mt) z2[t][mt] = z2[t][mt] + upk4(zrp[t] + 2 * mt);
        lnorm_c(z2[t], P + PB_ZN2G, P + PB_ZN2B, q);
        uint zp[8];
#pragma unroll
        for (int mt = 0; mt < 4; ++mt) {
          zp[2 * mt]     = pk2(z2[t][mt].x, z2[t][mt].y);
          zp[2 * mt + 1] = pk2(z2[t][mt].z, z2[t][mt].w);
          zCp[t][2 * mt] = zp[2 * mt]; zCp[t][2 * mt + 1] = zp[2 * mt + 1];
        }
        c2b_p(zp, zB[t][0], zB[t][1], lane);
      }

      // -- y branch --
      {
        f32x4 t4[2][4];
        layerB2<4>(zB[0], zB[1], LW, LB_YV, P + PB_YVB, t4[0], t4[1], lane, q);
#pragma unroll
        for (int mt = 0; mt < 4; ++mt) {
          stc(TH0, S64, mt, q, s, t4[0][mt]);
          stc(TH1, S64, mt, q, s, t4[1][mt]);
        }
      }

      uint yrp[2][8];
      {
        f32x4 yr[2][4];
        layerN2<4>(TH0, TH1, LW, LB_YOUT, P + PB_YOUTB, yr[0], yr[1], lane, q, s);
#pragma unroll
        for (int t = 0; t < 2; ++t) {
#pragma unroll
          for (int mt = 0; mt < 4; ++mt) yr[t][mt] = yr[t][mt] + upk4(yCp[t] + 2 * mt);
          lnorm_c(yr[t], P + PB_YN1G, P + PB_YN1B, q);
        }
#pragma unroll
        for (int mt = 0; mt < 4; ++mt) {
          stc(TH0, S64, mt, q, s, yr[0][mt]);
          stc(TH1, S64, mt, q, s, yr[1][mt]);
        }
#pragma unroll
        for (int t = 0; t < 2; ++t)
#pragma unroll
          for (int mt = 0; mt < 4; ++mt) {
            yrp[t][2 * mt]     = pk2(yr[t][mt].x, yr[t][mt].y);
            yrp[t][2 * mt + 1] = pk2(yr[t][mt].z, yr[t][mt].w);
          }
      }

      // y-FFN
      f32x4 y2[2][4];
      {
        f32x4 h8[2][8];
        layerN2<8>(TH0, TH1, LW, LB_YF1, P + PB_YF1B, h8[0], h8[1], lane, q, s);
        ffn2_via_th2(h8[0], h8[1], TH0, TH1, LW, LB_YF2, P + PB_YF2B,
                     y2[0], y2[1], lane, q, s);
      }
#pragma unroll
      for (int t = 0; t < 2; ++t) {
#pragma unroll
        for (int mt = 0; mt < 4; ++mt) y2[t][mt] = y2[t][mt] + upk4(yrp[t] + 2 * mt);
        lnorm_c(y2[t], P + PB_YN2G, P + PB_YN2B, q);
        uint yp[8];
#pragma unroll
        for (int mt = 0; mt < 4; ++mt) {
          yp[2 * mt]     = pk2(y2[t][mt].x, y2[t][mt].y);
          yp[2 * mt + 1] = pk2(y2[t][mt].z, y2[t][mt].w);
          yCp[t][2 * mt] = yp[2 * mt]; yCp[t][2 * mt + 1] = yp[2 * mt + 1];
        }
        c2b_p(yp, yB[t][0], yB[t][1], lane);
      }
    }

    // ---- out = (y @ W_out^T + b_out)[:, 0] per stream ----
#pragma unroll
    for (int t = 0; t < 2; ++t) {
      float acc = 0.f;
#pragma unroll
      for (int mt = 0; mt < 4; ++mt) {
        f32x4 w4 = *(const f32x4*)(P + PB_WOUT + mt * 16 + q * 4);
        acc += dot4(upk4(yCp[t] + 2 * mt), w4);
      }
      acc += __shfl_xor(acc, 16); acc += __shfl_xor(acc, 32);
      int orow = ic * 256 + wave * 16 + t * 128 + s;
      if (q == 0 && orow < p.nrows) p.out[orow] = acc + P[PB_BOUT];
    }
  }
}

extern "C" void kernel_launch(void* const* d_in, const int* in_sizes, int n_in,
                              void* d_out, int out_size, void* d_ws,
                              size_t ws_size, hipStream_t stream) {
  Params p;
  const float* const* in = (const float* const*)d_in;
  p.x        = in[0];  p.W_in     = in[1];  p.b_in     = in[2];
  p.g_in     = in[3];  p.be_in    = in[4];
  p.z_in_w   = in[5];  p.z_in_b   = in[6];
  p.z_out_w  = in[7];  p.z_out_b  = in[8];
  p.z_ffn_w1 = in[9];  p.z_ffn_b1 = in[10];
  p.z_ffn_w2 = in[11]; p.z_ffn_b2 = in[12];
  p.zn1_g    = in[13]; p.zn1_b    = in[14];
  p.zn2_g    = in[15]; p.zn2_b    = in[16];
  p.y_in_w   = in[17]; p.y_in_b   = in[18];
  p.y_out_w  = in[19]; p.y_out_b  = in[20];
  p.y_ffn_w1 = in[21]; p.y_ffn_b1 = in[22];
  p.y_ffn_w2 = in[23]; p.y_ffn_b2 = in[24];
  p.yn1_g    = in[25]; p.yn1_b    = in[26];
  p.yn2_g    = in[27]; p.yn2_b    = in[28];
  p.W_out    = in[29]; p.b_out    = in[30];
  p.out      = (float*)d_out;
  p.nrows    = in_sizes[0] / INDIM;

  if (ws_size < (size_t)NFRAG * 1024 + NPARAM * 4) return;
  ushort* wf = (ushort*)d_ws;

  hipLaunchKernelGGL(prepack_kernel, dim3(NFRAG + 1), dim3(64), 0, stream, p, wf);
  hipLaunchKernelGGL(trm_mfma_kernel, dim3(256), dim3(512), 0, stream, p, wf);
}